// Round 7
// baseline (677.415 us; speedup 1.0000x reference)
//
#include <hip/hip_runtime.h>
#include <hip/hip_bf16.h>
#include <cstdint>
#include <cstddef>

#define B_DIM 8
#define L_DIM 4096
#define D_INN 1024
#define H_DIM 1024
#define LATENTD 256
#define SEGLEN 128
#define KSUB 32
#define M_HALF (B_DIM * L_DIM)      // 32768
#define M_TOTAL (2 * M_HALF)        // 65536

typedef __attribute__((ext_vector_type(8))) short bf16x8;
typedef __attribute__((ext_vector_type(4))) float f32x4;

static __device__ __forceinline__ unsigned short f2bf(float x) {
  __hip_bfloat16 b = __float2bfloat16(x);
  return __builtin_bit_cast(unsigned short, b);
}

static __device__ __forceinline__ void async16(const unsigned short* g, unsigned short* l) {
  __builtin_amdgcn_global_load_lds(
      (const __attribute__((address_space(1))) unsigned int*)g,
      (__attribute__((address_space(3))) unsigned int*)l,
      16, 0, 0);
}

// ---------------- combined prep kernel ----------------
// grid (16,16,5):
//   z=0: WT  = transpose(W_proj)  (1024x1024 -> bf16)
//   z=1: WoutT = transpose(W_out) (1024x1024 -> bf16)
//   z=2: WcatT rows [0,256)   = transpose(W_mu) (1024x256)
//   z=3: WcatT rows [256,512) = transpose(W_lv)
//   z=4: decay vectors (only blocks y==0, x<4 active)
__global__ __launch_bounds__(256) void prep_kernel(const float* __restrict__ W_proj,
                                                   const float* __restrict__ a_raw,
                                                   const float* __restrict__ Wo,
                                                   const float* __restrict__ Wm,
                                                   const float* __restrict__ Wl,
                                                   unsigned short* __restrict__ WT,
                                                   float* __restrict__ avec,
                                                   float* __restrict__ gvec,
                                                   float* __restrict__ a128v,
                                                   unsigned short* __restrict__ WoutT,
                                                   unsigned short* __restrict__ WcatT) {
  const int z = blockIdx.z;
  if (z == 4) {
    if (blockIdx.y != 0 || blockIdx.x >= 4) return;
    int h = blockIdx.x * 256 + threadIdx.x;
    float a = 1.f / (1.f + expf(-a_raw[h]));
    float p = 1.f, g = 0.f;
    for (int j = 0; j < SEGLEN; j++) { g += p; p *= a; }
    avec[h] = a; gvec[h] = g; a128v[h] = p;   // p = a^128
    return;
  }
  __shared__ float tile[64][65];
  const float* src; unsigned short* dst; int N; int rowoff;
  if (z == 0)      { src = W_proj; dst = WT;    N = 1024; rowoff = 0; }
  else if (z == 1) { src = Wo;     dst = WoutT; N = 1024; rowoff = 0; }
  else if (z == 2) { src = Wm;     dst = WcatT; N = 256;  rowoff = 0; }
  else             { src = Wl;     dst = WcatT; N = 256;  rowoff = 256; }
  int k0 = blockIdx.x * 64, n0 = blockIdx.y * 64;
  if (n0 >= N) return;
  for (int i = threadIdx.x; i < 64 * 64; i += 256) {
    int kk = i >> 6, nn = i & 63;
    tile[kk][nn] = src[(size_t)(k0 + kk) * N + n0 + nn];
  }
  __syncthreads();
  for (int i = threadIdx.x; i < 64 * 64; i += 256) {
    int nn = i >> 6, kk = i & 63;
    dst[(size_t)(rowoff + n0 + nn) * 1024 + k0 + kk] = f2bf(tile[kk][nn]);
  }
}

// ---------------- main GEMM + segment decay reduction (persistent) ----------
// Persistent 256-block version (R6 verified) with COUNTED-LGKM schedule:
// all 24 ds_reads (a0,b0,a1,b1) issue at the top of the tile, BEFORE MFMA0.
// The compiler's dependency waitcnts emit a partial lgkmcnt before MFMA0
// (phase-0 ready, phase-1 in flight); phase-1's read latency hides under
// MFMA0's ~1242cy. The explicit lgkmcnt(0) before the mid-barrier (required:
// STAGEB clobbers buf) is then a near-free wait. A staging repacked to
// 4x ds_write_b128 (same LDS image: LDS[r*64+(c^(r&7))*8..] = G[r][c*8..]).
// vmcnt counting unchanged from R6: at end-of-tile vmcnt(4) the outstanding
// queue is [STAGEB(t+1)] [ALOAD(t+2) x8] [STAGEB(t+2) x4] -> drains A+old B.

__global__ __launch_bounds__(512) void gemm_seg_kernel(const float* __restrict__ Atgt,
                                                       const float* __restrict__ Adec,
                                                       const unsigned short* __restrict__ WT,
                                                       const float* __restrict__ avec,
                                                       const float* __restrict__ gvec,
                                                       const float* __restrict__ bproj,
                                                       float* __restrict__ Dred) {
  __shared__ alignas(16) unsigned short lds[65536];  // 128 KiB: A [0,32768), B [32768,65536)

  const int t = threadIdx.x;          // 0..511
  const int lane = t & 63;
  const int wave = t >> 6;            // 0..7
  const int wr = wave >> 2;           // 0..1  M-half (= segment within tile)
  const int wc = wave & 3;            // 0..3  N-quarter
  const int lo = lane & 15;
  const int q = lane >> 4;

  const int bid = blockIdx.x;         // 0..255
  const int bn = (bid >> 3) & 3;                          // fixed per block
  const int bm0 = ((bid & 7) * 128 + (bid >> 3)) >> 2;    // item 0's bm; bm(it)=bm0+8it

  // ---- B staging (global_load_lds, pre-swizzled source; depends on kk only) ----
  const int tr = t >> 3;                                  // row-within-64
  const int csw = (((t & 7) ^ (tr & 7)) * 8);             // pre-swizzled col (shorts)
  const unsigned short* Bsrc = WT + ((size_t)(bn * 256 + tr)) * 1024 + csw;
  unsigned short* ldsB = lds + 32768 + t * 8;

#define STAGEB(buf_, gt_)                                                          \
  {                                                                                \
    _Pragma("unroll")                                                              \
    for (int hl = 0; hl < 4; ++hl) {                                               \
      const int half_ = hl >> 1, l_ = hl & 1;                                      \
      async16(Bsrc + (size_t)(half_ * 128 + l_ * 64) * 1024 + ((gt_) & 15) * 64,   \
              ldsB + (buf_) * 16384 + half_ * 8192 + l_ * 4096);                   \
    }                                                                              \
  }

  // ---- A reg-staging (fused fp32 read + convert; b128-write mapping) ----
  // Thread covers rows {(t>>3) + 64*i, i<4}, fp32 cols [(t&7)*8, +8) of the
  // tile window: per row 2 float4 loads -> one short8 ds_write_b128.
  // Wave = 8 rows x full 64 cols = contiguous 256B/row segments (coalesced).
  // LDS image (identical to R2-R6): LDS[r*64 + (c^(r&7))*8 ..+8] = G[r][c*8..]
  const float* Afp = ((bm0 < 128) ? Atgt : Adec) + ((size_t)(bm0 & 127)) * 256 * 1024;
  const int arow = t >> 3;            // 0..63
  const int achk = t & 7;             // 0..7
  const float* Ath = Afp + ((size_t)arow) * 1024 + achk * 8;
  unsigned short* ldsAw = lds + arow * 64 + ((achk ^ (arow & 7)) * 8);  // i adds 4096 shorts

  float4 fA[4][2];

#define ALOAD(gt_)                                                                 \
  {                                                                                \
    _Pragma("unroll")                                                              \
    for (int i_ = 0; i_ < 4; ++i_) {                                               \
      const float* p_ = Ath + (size_t)i_ * 65536 +                                 \
                        (size_t)((gt_) >> 4) * 2097152 + ((gt_) & 15) * 64;        \
      fA[i_][0] = *(const float4*)(p_);                                            \
      fA[i_][1] = *(const float4*)(p_ + 4);                                        \
    }                                                                              \
  }

#define AWRITE(buf_)                                                               \
  {                                                                                \
    _Pragma("unroll")                                                              \
    for (int i_ = 0; i_ < 4; ++i_) {                                               \
      bf16x8 o_;                                                                   \
      o_[0] = (short)f2bf(fA[i_][0].x); o_[1] = (short)f2bf(fA[i_][0].y);          \
      o_[2] = (short)f2bf(fA[i_][0].z); o_[3] = (short)f2bf(fA[i_][0].w);          \
      o_[4] = (short)f2bf(fA[i_][1].x); o_[5] = (short)f2bf(fA[i_][1].y);          \
      o_[6] = (short)f2bf(fA[i_][1].z); o_[7] = (short)f2bf(fA[i_][1].w);          \
      *(bf16x8*)(ldsAw + (buf_) * 16384 + i_ * 4096) = o_;                         \
    }                                                                              \
  }

  // ---- ds_read addressing (swizzled; unchanged from verified R2-R6) ----
  const unsigned short* ArdB = lds + (size_t)(wr * 128 + lo) * 64;
  const unsigned short* BrdB = lds + 32768 + (size_t)(wc * 64 + lo) * 64;
  const int ch0 = ((q ^ (lo & 7)) * 8);        // k-slice 0 chunk (shorts)
  const int ch1 = (((4 + q) ^ (lo & 7)) * 8);  // k-slice 1 chunk (shorts)

  f32x4 acc[8][4];
#pragma unroll
  for (int i = 0; i < 8; i++)
#pragma unroll
    for (int j = 0; j < 4; j++) acc[i][j] = (f32x4){0.f, 0.f, 0.f, 0.f};

  // ---- prologue (once per block): buf0<-gt0, buf1<-gt1, regs<-gt2 in flight ----
  ALOAD(0);
  __builtin_amdgcn_sched_barrier(0);
  STAGEB(0, 0);
  STAGEB(1, 1);
  __builtin_amdgcn_sched_barrier(0);
  asm volatile("s_waitcnt vmcnt(8)" ::: "memory");   // ALOAD(0) landed (8 newest = B asyncs)
  AWRITE(0);
  ALOAD(1);
  __builtin_amdgcn_sched_barrier(0);
  asm volatile("s_waitcnt vmcnt(0)" ::: "memory");   // ALOAD(1) + all B landed
  AWRITE(1);
  ALOAD(2);                                          // flies across gt 0
  __builtin_amdgcn_sched_barrier(0);
  asm volatile("s_waitcnt lgkmcnt(0)" ::: "memory");
  __builtin_amdgcn_sched_barrier(0);

  int buf = 0;
  for (int gt = 0; gt < 64; ++gt) {                  // 4 items x 16 K-tiles, continuous
    if (gt == 63) asm volatile("s_waitcnt vmcnt(0)" ::: "memory");
    asm volatile("s_barrier" ::: "memory");          // top: publish buf
    __builtin_amdgcn_sched_barrier(0);

    const unsigned short* Ab = ArdB + buf * 16384;
    const unsigned short* Bb = BrdB + buf * 16384;

    // ---- issue ALL 24 reads up front (counted-lgkm: phase-1 hides under MFMA0)
    bf16x8 b0[4], a0[8], a1[8], b1[4];
#pragma unroll
    for (int j = 0; j < 4; j++) b0[j] = *(const bf16x8*)&Bb[j * 1024 + ch0];
#pragma unroll
    for (int i = 0; i < 8; i++) a0[i] = *(const bf16x8*)&Ab[i * 1024 + ch0];
#pragma unroll
    for (int j = 0; j < 4; j++) b1[j] = *(const bf16x8*)&Bb[j * 1024 + ch1];
#pragma unroll
    for (int i = 0; i < 8; i++) a1[i] = *(const bf16x8*)&Ab[i * 1024 + ch1];
    __builtin_amdgcn_sched_barrier(0);

    // MFMA0: compiler auto-inserts a PARTIAL lgkmcnt (a0/b0 ready, a1/b1 fly)
#pragma unroll
    for (int i = 0; i < 8; i++)
#pragma unroll
      for (int j = 0; j < 4; j++)
        acc[i][j] = __builtin_amdgcn_mfma_f32_16x16x32_bf16(a0[i], b0[j], acc[i][j], 0, 0, 0);
    __builtin_amdgcn_sched_barrier(0);

    // all reads of this buffer landed in regs (near-free: hidden under MFMA0)
    asm volatile("s_waitcnt lgkmcnt(0)" ::: "memory");
    __builtin_amdgcn_sched_barrier(0);
    asm volatile("s_barrier" ::: "memory");          // mid: all waves past buf reads

    if (gt < 62) STAGEB(buf, gt + 2);                // clobber-safe

    __builtin_amdgcn_s_setprio(1);
#pragma unroll
    for (int i = 0; i < 8; i++)
#pragma unroll
      for (int j = 0; j < 4; j++)
        acc[i][j] = __builtin_amdgcn_mfma_f32_16x16x32_bf16(a1[i], b1[j], acc[i][j], 0, 0, 0);
    __builtin_amdgcn_s_setprio(0);
    __builtin_amdgcn_sched_barrier(0);

    if (gt < 62) {
      // outstanding (oldest->newest): [STAGEB(gt+1)] [ALOAD(gt+2) x8] [STAGEB(gt+2) x4]
      // vmcnt(4): leaves only the 4 newest B-asyncs in flight.
      asm volatile("s_waitcnt vmcnt(4)" ::: "memory");
      __builtin_amdgcn_sched_barrier(0);
      AWRITE(buf);                   // cvt + 4x swizzled ds_write_b128
      if (gt < 61) ALOAD(gt + 3);    // regs free -> next A flies a FULL tile
      __builtin_amdgcn_sched_barrier(0);
      asm volatile("s_waitcnt lgkmcnt(0)" ::: "memory");  // AWRITE visible before top barrier
      __builtin_amdgcn_sched_barrier(0);
    }

    // ---- per-item epilogue at gt&15==15: Horner decay reduce, store, reset ----
    if ((gt & 15) == 15) {
      const int itv = gt >> 4;
      const int seg = (bm0 + 8 * itv) * 2 + wr;
#pragma unroll
      for (int j = 0; j < 4; ++j) {
        const int h = bn * 256 + wc * 64 + j * 16 + lo;
        const float a = avec[h];
        const float a2 = a * a, a4 = a2 * a2, a8 = a4 * a4, a16 = a8 * a8;
        float P = 0.f;
#pragma unroll
        for (int i = 0; i < 8; ++i) {
          f32x4 u = acc[i][j];
          float vi = ((u.x * a + u.y) * a + u.z) * a + u.w;
          P = P * a16 + vi;
        }
        const float qf = (q == 3) ? 1.f : ((q == 2) ? a4 : ((q == 1) ? a8 : a8 * a4));
        P *= qf;
        P += __shfl_xor(P, 16);
        P += __shfl_xor(P, 32);
        if (q == 0)
          Dred[(size_t)seg * H_DIM + h] = P + bproj[h] * gvec[h];
      }
#pragma unroll
      for (int i = 0; i < 8; i++)
#pragma unroll
        for (int j = 0; j < 4; j++) acc[i][j] = (f32x4){0.f, 0.f, 0.f, 0.f};
    }
    buf ^= 1;
  }
#undef STAGEB
#undef ALOAD
#undef AWRITE
}

// ---------------- prefix scan over k + hT (bf16 out) ----------------
__global__ __launch_bounds__(256) void state_kernel(const float* __restrict__ Dred,
                                                    const float* __restrict__ a128v,
                                                    unsigned short* __restrict__ hTbf) {
  int idx = blockIdx.x * 256 + threadIdx.x;  // b*1024 + h, 8192 total
  int b = idx >> 10, h = idx & 1023;
  const float* S = Dred + (size_t)b * KSUB * H_DIM + h;            // corr stream
  const float* Dd = Dred + (size_t)(B_DIM + b) * KSUB * H_DIM + h; // dec stream
  float A = a128v[h];
  float C = 0.f;
  for (int k = 0; k < KSUB; k++) {
    hTbf[((size_t)(b * KSUB + k)) * H_DIM + h] = f2bf(fmaf(A, C, Dd[(size_t)k * H_DIM]));
    C = fmaf(A, C, S[(size_t)k * H_DIM]);
  }
}

// ---------------- MFMA heads ----------------
// head1: y = silu(hT @ W_out + b_out)   M=256, N=1024, K=1024, out bf16
__global__ __launch_bounds__(256) void head1_kernel(const unsigned short* __restrict__ Abf,
                                                    const unsigned short* __restrict__ Bt,
                                                    const float* __restrict__ bias,
                                                    unsigned short* __restrict__ ybf) {
  __shared__ alignas(16) unsigned short As[128 * 32];
  __shared__ alignas(16) unsigned short Bs[128 * 32];
  const int t = threadIdx.x;
  const int lane = t & 63, wave = t >> 6;
  const int bm = blockIdx.x, bn = blockIdx.y;
  const int lo = lane & 15, q = lane >> 4;
  const int wm = wave & 1, wn = wave >> 1;

  f32x4 acc[4][4];
#pragma unroll
  for (int i = 0; i < 4; i++)
#pragma unroll
    for (int j = 0; j < 4; j++) acc[i][j] = (f32x4){0.f, 0.f, 0.f, 0.f};

  const int r0 = t >> 2;
  const int c0 = (t & 3) * 8;
  const unsigned short* Ag0 = Abf + ((size_t)bm * 128 + r0) * 1024 + c0;
  const unsigned short* Ag1 = Abf + ((size_t)bm * 128 + 64 + r0) * 1024 + c0;
  const unsigned short* Bg0 = Bt + ((size_t)bn * 128 + r0) * 1024 + c0;
  const unsigned short* Bg1 = Bt + ((size_t)bn * 128 + 64 + r0) * 1024 + c0;
  unsigned short* Al0 = &As[t * 8];
  unsigned short* Al1 = &As[(256 + t) * 8];
  unsigned short* Bl0 = &Bs[t * 8];
  unsigned short* Bl1 = &Bs[(256 + t) * 8];

  for (int kk = 0; kk < 1024; kk += 32) {
    async16(Ag0 + kk, Al0);
    async16(Ag1 + kk, Al1);
    async16(Bg0 + kk, Bl0);
    async16(Bg1 + kk, Bl1);
    __syncthreads();
    bf16x8 af[4], bv[4];
#pragma unroll
    for (int i = 0; i < 4; i++)
      af[i] = *(const bf16x8*)&As[(wm * 64 + i * 16 + lo) * 32 + q * 8];
#pragma unroll
    for (int j = 0; j < 4; j++)
      bv[j] = *(const bf16x8*)&Bs[(wn * 64 + j * 16 + lo) * 32 + q * 8];
#pragma unroll
    for (int i = 0; i < 4; i++)
#pragma unroll
      for (int j = 0; j < 4; j++)
        acc[i][j] = __builtin_amdgcn_mfma_f32_16x16x32_bf16(af[i], bv[j], acc[i][j], 0, 0, 0);
    __syncthreads();
  }

#pragma unroll
  for (int j = 0; j < 4; j++) {
    const int col = bn * 128 + wn * 64 + j * 16 + lo;
    const float bb = bias[col];
#pragma unroll
    for (int i = 0; i < 4; i++) {
#pragma unroll
      for (int r = 0; r < 4; r++) {
        const int row = bm * 128 + wm * 64 + i * 16 + q * 4 + r;
        float z = acc[i][j][r] + bb;
        float y = z / (1.f + expf(-z));
        ybf[(size_t)row * 1024 + col] = f2bf(y);
      }
    }
  }
}

// head2: [mu|lv] = y @ [W_mu|W_lv] + [b_mu|b_lv]   M=256, N=512, K=1024, out fp32
__global__ __launch_bounds__(256) void head2_kernel(const unsigned short* __restrict__ Abf,
                                                    const unsigned short* __restrict__ Bt,
                                                    const float* __restrict__ bmu,
                                                    const float* __restrict__ blv,
                                                    float* __restrict__ out) {
  __shared__ alignas(16) unsigned short As[128 * 32];
  __shared__ alignas(16) unsigned short Bs[128 * 32];
  const int t = threadIdx.x;
  const int lane = t & 63, wave = t >> 6;
  const int bm = blockIdx.x, bn = blockIdx.y;   // bn 0..3
  const int lo = lane & 15, q = lane >> 4;
  const int wm = wave & 1, wn = wave >> 1;

  f32x4 acc[4][4];
#pragma unroll
  for (int i = 0; i < 4; i++)
#pragma unroll
    for (int j = 0; j < 4; j++) acc[i][j] = (f32x4){0.f, 0.f, 0.f, 0.f};

  const int r0 = t >> 2;
  const int c0 = (t & 3) * 8;
  const unsigned short* Ag0 = Abf + ((size_t)bm * 128 + r0) * 1024 + c0;
  const unsigned short* Ag1 = Abf + ((size_t)bm * 128 + 64 + r0) * 1024 + c0;
  const unsigned short* Bg0 = Bt + ((size_t)bn * 128 + r0) * 1024 + c0;
  const unsigned short* Bg1 = Bt + ((size_t)bn * 128 + 64 + r0) * 1024 + c0;
  unsigned short* Al0 = &As[t * 8];
  unsigned short* Al1 = &As[(256 + t) * 8];
  unsigned short* Bl0 = &Bs[t * 8];
  unsigned short* Bl1 = &Bs[(256 + t) * 8];

  for (int kk = 0; kk < 1024; kk += 32) {
    async16(Ag0 + kk, Al0);
    async16(Ag1 + kk, Al1);
    async16(Bg0 + kk, Bl0);
    async16(Bg1 + kk, Bl1);
    __syncthreads();
    bf16x8 af[4], bv[4];
#pragma unroll
    for (int i = 0; i < 4; i++)
      af[i] = *(const bf16x8*)&As[(wm * 64 + i * 16 + lo) * 32 + q * 8];
#pragma unroll
    for (int j = 0; j < 4; j++)
      bv[j] = *(const bf16x8*)&Bs[(wn * 64 + j * 16 + lo) * 32 + q * 8];
#pragma unroll
    for (int i = 0; i < 4; i++)
#pragma unroll
      for (int j = 0; j < 4; j++)
        acc[i][j] = __builtin_amdgcn_mfma_f32_16x16x32_bf16(af[i], bv[j], acc[i][j], 0, 0, 0);
    __syncthreads();
  }

#pragma unroll
  for (int j = 0; j < 4; j++) {
    const int col = bn * 128 + wn * 64 + j * 16 + lo;   // 0..511
    const float bb = (col < 256) ? bmu[col] : blv[col - 256];
    float* dst = (col < 256) ? (out + col) : (out + 65536 + (col - 256));
#pragma unroll
    for (int i = 0; i < 4; i++) {
#pragma unroll
      for (int r = 0; r < 4; r++) {
        const int row = bm * 128 + wm * 64 + i * 16 + q * 4 + r;
        dst[(size_t)row * 256] = acc[i][j][r] + bb;
      }
    }
  }
}

// ---------------- launcher ----------------
extern "C" void kernel_launch(void* const* d_in, const int* in_sizes, int n_in,
                              void* d_out, int out_size, void* d_ws, size_t ws_size,
                              hipStream_t stream) {
  const float* decoder = (const float*)d_in[0];
  const float* targets = (const float*)d_in[1];
  const float* W_proj = (const float*)d_in[2];
  const float* b_proj = (const float*)d_in[3];
  const float* a_raw = (const float*)d_in[4];
  const float* W_out = (const float*)d_in[5];
  const float* b_out = (const float*)d_in[6];
  const float* W_mu = (const float*)d_in[7];
  const float* b_mu = (const float*)d_in[8];
  const float* W_lv = (const float*)d_in[9];
  const float* b_lv = (const float*)d_in[10];
  float* out = (float*)d_out;

  char* ws = (char*)d_ws;
  unsigned short* WT = (unsigned short*)(ws + 134217728);         // 2097152 B
  float* avec = (float*)(ws + 136314880);                         // 4096 B
  float* gvec = (float*)(ws + 136318976);                         // 4096 B
  float* a128v = (float*)(ws + 136323072);                        // 4096 B
  float* DredP = (float*)(ws + 136327168);                        // 2097152 B -> end 138424320
  // low workspace region:
  unsigned short* hTbf = (unsigned short*)ws;                     // 524288 B
  unsigned short* ybf = (unsigned short*)(ws + 524288);           // 524288 B
  unsigned short* WoutT = (unsigned short*)(ws + 1048576);        // 2097152 B
  unsigned short* WcatT = (unsigned short*)(ws + 3145728);        // 1048576 B

  prep_kernel<<<dim3(16, 16, 5), 256, 0, stream>>>(W_proj, a_raw, W_out, W_mu, W_lv,
                                                   WT, avec, gvec, a128v, WoutT, WcatT);
  gemm_seg_kernel<<<256, 512, 0, stream>>>(targets, decoder, WT, avec, gvec, b_proj, DredP);
  state_kernel<<<32, 256, 0, stream>>>(DredP, a128v, hTbf);
  head1_kernel<<<dim3(2, 8), 256, 0, stream>>>(hTbf, WoutT, b_out, ybf);
  head2_kernel<<<dim3(2, 4), 256, 0, stream>>>(ybf, WcatT, b_mu, b_lv, out);
}

// Round 8
// 530.988 us; speedup vs baseline: 1.2758x; 1.2758x over previous
//
#include <hip/hip_runtime.h>
#include <hip/hip_bf16.h>
#include <cstdint>
#include <cstddef>

#define B_DIM 8
#define L_DIM 4096
#define D_INN 1024
#define H_DIM 1024
#define LATENTD 256
#define SEGLEN 128
#define KSUB 32
#define M_HALF (B_DIM * L_DIM)      // 32768
#define M_TOTAL (2 * M_HALF)        // 65536

typedef __attribute__((ext_vector_type(8))) short bf16x8;
typedef __attribute__((ext_vector_type(4))) float f32x4;

static __device__ __forceinline__ unsigned short f2bf(float x) {
  __hip_bfloat16 b = __float2bfloat16(x);
  return __builtin_bit_cast(unsigned short, b);
}

static __device__ __forceinline__ void async16(const unsigned short* g, unsigned short* l) {
  __builtin_amdgcn_global_load_lds(
      (const __attribute__((address_space(1))) unsigned int*)g,
      (__attribute__((address_space(3))) unsigned int*)l,
      16, 0, 0);
}

// ---------------- combined prep kernel (unchanged, R4-verified) ----------------
__global__ __launch_bounds__(256) void prep_kernel(const float* __restrict__ W_proj,
                                                   const float* __restrict__ a_raw,
                                                   const float* __restrict__ Wo,
                                                   const float* __restrict__ Wm,
                                                   const float* __restrict__ Wl,
                                                   unsigned short* __restrict__ WT,
                                                   float* __restrict__ avec,
                                                   float* __restrict__ gvec,
                                                   float* __restrict__ a128v,
                                                   unsigned short* __restrict__ WoutT,
                                                   unsigned short* __restrict__ WcatT) {
  const int z = blockIdx.z;
  if (z == 4) {
    if (blockIdx.y != 0 || blockIdx.x >= 4) return;
    int h = blockIdx.x * 256 + threadIdx.x;
    float a = 1.f / (1.f + expf(-a_raw[h]));
    float p = 1.f, g = 0.f;
    for (int j = 0; j < SEGLEN; j++) { g += p; p *= a; }
    avec[h] = a; gvec[h] = g; a128v[h] = p;   // p = a^128
    return;
  }
  __shared__ float tile[64][65];
  const float* src; unsigned short* dst; int N; int rowoff;
  if (z == 0)      { src = W_proj; dst = WT;    N = 1024; rowoff = 0; }
  else if (z == 1) { src = Wo;     dst = WoutT; N = 1024; rowoff = 0; }
  else if (z == 2) { src = Wm;     dst = WcatT; N = 256;  rowoff = 0; }
  else             { src = Wl;     dst = WcatT; N = 256;  rowoff = 256; }
  int k0 = blockIdx.x * 64, n0 = blockIdx.y * 64;
  if (n0 >= N) return;
  for (int i = threadIdx.x; i < 64 * 64; i += 256) {
    int kk = i >> 6, nn = i & 63;
    tile[kk][nn] = src[(size_t)(k0 + kk) * N + n0 + nn];
  }
  __syncthreads();
  for (int i = threadIdx.x; i < 64 * 64; i += 256) {
    int nn = i >> 6, kk = i & 63;
    dst[(size_t)(rowoff + n0 + nn) * 1024 + k0 + kk] = f2bf(tile[kk][nn]);
  }
}

// ---------------- main GEMM + segment decay reduction (2 blocks/CU) ----------
// R7 post-mortem: counted-lgkm spilled (acc128+24frags > 128 VGPR). R6 at
// 2 waves/SIMD is latency-bound (all pipes <35%). THIS version doubles TLP:
// BM=256,BN=128,BK=32, 512 thr, 8 waves (4Mx2N), wave tile 64x64 ->
// acc[4][4]=64 VGPR (total ~120 <=128 -> 4 waves/SIMD, launch_bounds(512,4)),
// LDS 50KB -> 2 persistent blocks/CU. One block's stalls hide under the
// sibling's MFMA (the m97 mechanism).
// BK=32 paired-row LDS layout (rows are 64B; old swizzle dies):
//   addr_short(r,c) = (r>>1)*64 + (r&1)*32 + ((c ^ ((r>>1)&3))*8), c in 0..3
// -> balanced 8-lanes-per-slot-class on ds_read_b128 (read swizzle reduces to
//    q^((lo>>1)&3), lane-constant) and on the staging writes.
// B staged via async16 (1/thread/tile, dest linear t*16, source pre-swizzled
// through the same bijection). A fp32 reg-staged (4 contiguous float4 =
// 16 floats/thread), cvt+2x ds_write_b128.
// Counted vmcnt: steady wait = vmcnt(1): queue oldest->newest at the wait is
// [B(gt+1)][A(gt+2)x4][B(gt+2)] -> drains A(gt+2)+B(gt+1), keeps newest B.
// Grid 512 = 8 XCD x 64: bn=(bid>>3)&7, bm(it) = (bid&7)*32 + (bid>>6) + 8it.

__global__ __launch_bounds__(512, 4) void gemm_seg_kernel(const float* __restrict__ Atgt,
                                                          const float* __restrict__ Adec,
                                                          const unsigned short* __restrict__ WT,
                                                          const float* __restrict__ avec,
                                                          const float* __restrict__ gvec,
                                                          const float* __restrict__ bproj,
                                                          float* __restrict__ Dred) {
  __shared__ alignas(16) unsigned short lds[24576];  // 48KB: A bufs [0,16384), B bufs [16384,24576)
  __shared__ float redLds[4][128];                   // 2KB epilogue combine

  const int t = threadIdx.x;          // 0..511
  const int lane = t & 63;
  const int wave = t >> 6;            // 0..7
  const int wr = wave >> 1;           // 0..3  M-quarter (64 rows)
  const int wc = wave & 1;            // 0..1  N-half (64 cols)
  const int lo = lane & 15;
  const int q = lane >> 4;

  const int bid = blockIdx.x;         // 0..511
  const int bn = (bid >> 3) & 7;                       // 0..7 (N=1024/128), fixed
  const int bm0 = (bid & 7) * 32 + (bid >> 6);         // item it: bm = bm0 + 8*it

  // ---- B staging: 1 async16/thread/tile. Dest linear t*16B; source
  // pre-swizzled: dest (r = (t>>3)*2+((t>>2)&1), swz-slot t&3) holds logical
  // chunk bc = (t&3) ^ ((t>>3)&3) of WT row bn*128+r.
  const int br = (t >> 3) * 2 + ((t >> 2) & 1);
  const int bc = (t & 3) ^ ((t >> 3) & 3);
  const unsigned short* Bsrc = WT + (size_t)(bn * 128 + br) * 1024 + bc * 8;
  unsigned short* ldsBd = lds + 16384 + t * 8;

#define STAGEB(buf_, gt_) async16(Bsrc + ((gt_) & 31) * 32, ldsBd + (buf_) * 4096);

  // ---- A reg-staging: thread covers fp32 row ar=t>>1, half ah=t&1:
  // 16 contiguous floats -> 4 float4 -> chunks c0=ah*2, c0+1 (2x b128 write).
  const float* Afp = ((bm0 < 128) ? Atgt : Adec) + ((size_t)(bm0 & 127)) * 256 * 1024;
  const float* Ath = Afp + ((size_t)(t >> 1)) * 1024 + (t & 1) * 16;
  unsigned short* ldsAw = lds + (t >> 2) * 64 + ((t >> 1) & 1) * 32;  // base(r)
  const int awr_s0 = (((t & 1) * 2) ^ ((t >> 2) & 3)) * 8;
  const int awr_s1 = ((((t & 1) * 2) | 1) ^ ((t >> 2) & 3)) * 8;

  float4 fA[4];

#define ALOAD(gt_)                                                                 \
  {                                                                                \
    const float* p_ = Ath + (size_t)((gt_) >> 5) * 2097152 + ((gt_) & 31) * 32;    \
    fA[0] = ((const float4*)p_)[0]; fA[1] = ((const float4*)p_)[1];                \
    fA[2] = ((const float4*)p_)[2]; fA[3] = ((const float4*)p_)[3];                \
  }

#define AWRITE(buf_)                                                               \
  {                                                                                \
    bf16x8 o0_, o1_;                                                               \
    o0_[0] = (short)f2bf(fA[0].x); o0_[1] = (short)f2bf(fA[0].y);                  \
    o0_[2] = (short)f2bf(fA[0].z); o0_[3] = (short)f2bf(fA[0].w);                  \
    o0_[4] = (short)f2bf(fA[1].x); o0_[5] = (short)f2bf(fA[1].y);                  \
    o0_[6] = (short)f2bf(fA[1].z); o0_[7] = (short)f2bf(fA[1].w);                  \
    o1_[0] = (short)f2bf(fA[2].x); o1_[1] = (short)f2bf(fA[2].y);                  \
    o1_[2] = (short)f2bf(fA[2].z); o1_[3] = (short)f2bf(fA[2].w);                  \
    o1_[4] = (short)f2bf(fA[3].x); o1_[5] = (short)f2bf(fA[3].y);                  \
    o1_[6] = (short)f2bf(fA[3].z); o1_[7] = (short)f2bf(fA[3].w);                  \
    *(bf16x8*)(ldsAw + (buf_) * 8192 + awr_s0) = o0_;                              \
    *(bf16x8*)(ldsAw + (buf_) * 8192 + awr_s1) = o1_;                              \
  }

  // ---- ds_read addressing: row = wr*64+i*16+lo (A) / wc*64+j*16+lo (B),
  // chunk q. Swizzle term (row>>1)&3 == (lo>>1)&3 (i*8, wr*32 ≡ 0 mod 4).
  const int chsw = (q ^ ((lo >> 1) & 3)) * 8;
  const unsigned short* ArdB = lds + (wr * 32 + (lo >> 1)) * 64 + (lo & 1) * 32 + chsw;
  const unsigned short* BrdB = lds + 16384 + (wc * 32 + (lo >> 1)) * 64 + (lo & 1) * 32 + chsw;

  f32x4 acc[4][4];
#pragma unroll
  for (int i = 0; i < 4; i++)
#pragma unroll
    for (int j = 0; j < 4; j++) acc[i][j] = (f32x4){0.f, 0.f, 0.f, 0.f};

  // ---- prologue: buf0<-gt0, buf1<-gt1 staged; A(gt2) in flight ----
  ALOAD(0);
  __builtin_amdgcn_sched_barrier(0);
  STAGEB(0, 0);
  STAGEB(1, 1);
  __builtin_amdgcn_sched_barrier(0);
  asm volatile("s_waitcnt vmcnt(2)" ::: "memory");   // A(0) landed (B0,B1 newest)
  AWRITE(0);
  ALOAD(1);
  __builtin_amdgcn_sched_barrier(0);
  asm volatile("s_waitcnt vmcnt(0)" ::: "memory");   // A(1)+B0+B1 landed
  AWRITE(1);
  ALOAD(2);                                          // flies across tile 0
  __builtin_amdgcn_sched_barrier(0);
  asm volatile("s_waitcnt lgkmcnt(0)" ::: "memory");
  __builtin_amdgcn_sched_barrier(0);

  int buf = 0;
  for (int gt = 0; gt < 128; ++gt) {                 // 4 items x 32 K-tiles
    asm volatile("s_barrier" ::: "memory");          // top: publish buf
    __builtin_amdgcn_sched_barrier(0);

    const unsigned short* Ab = ArdB + buf * 8192;
    const unsigned short* Bb = BrdB + buf * 4096;

    bf16x8 bv[4], av[4];
#pragma unroll
    for (int j = 0; j < 4; j++) bv[j] = *(const bf16x8*)&Bb[j * 512];
#pragma unroll
    for (int i = 0; i < 4; i++) av[i] = *(const bf16x8*)&Ab[i * 512];
    __builtin_amdgcn_sched_barrier(0);

    __builtin_amdgcn_s_setprio(1);
#pragma unroll
    for (int i = 0; i < 4; i++)
#pragma unroll
      for (int j = 0; j < 4; j++)
        acc[i][j] = __builtin_amdgcn_mfma_f32_16x16x32_bf16(av[i], bv[j], acc[i][j], 0, 0, 0);
    __builtin_amdgcn_s_setprio(0);
    __builtin_amdgcn_sched_barrier(0);

    asm volatile("s_waitcnt lgkmcnt(0)" ::: "memory");
    __builtin_amdgcn_sched_barrier(0);
    asm volatile("s_barrier" ::: "memory");          // mid: all waves past buf reads

    if (gt < 126) {
      STAGEB(buf, gt + 2);
      // queue oldest->newest: [B(gt+1)] [A(gt+2)x4] [B(gt+2)] -> vmcnt(1)
      asm volatile("s_waitcnt vmcnt(1)" ::: "memory");
      __builtin_amdgcn_sched_barrier(0);
      AWRITE(buf);
      if (gt < 125) ALOAD(gt + 3);
      __builtin_amdgcn_sched_barrier(0);
      asm volatile("s_waitcnt lgkmcnt(0)" ::: "memory");  // A writes visible pre-barrier
      __builtin_amdgcn_sched_barrier(0);
    } else if (gt == 126) {
      asm volatile("s_waitcnt vmcnt(0)" ::: "memory");    // drain last B(127)
    }

    // ---- per-item epilogue (every 32 tiles): Horner + cross-pair combine ----
    if ((gt & 31) == 31) {
      const int bm = bm0 + 8 * (gt >> 5);
      float D64[4];
#pragma unroll
      for (int j = 0; j < 4; ++j) {
        const int col = wc * 64 + j * 16 + lo;       // 0..127 within block
        const float a = avec[bn * 128 + col];
        const float a2 = a * a, a4 = a2 * a2, a8 = a4 * a4, a16 = a8 * a8;
        float P = 0.f;
#pragma unroll
        for (int i = 0; i < 4; ++i) {
          f32x4 u = acc[i][j];
          float vi = ((u.x * a + u.y) * a + u.z) * a + u.w;
          P = P * a16 + vi;
        }
        const float qf = (q == 3) ? 1.f : ((q == 2) ? a4 : ((q == 1) ? a8 : a8 * a4));
        P *= qf;                                     // weight now a^(63-row64)
        P += __shfl_xor(P, 16);
        P += __shfl_xor(P, 32);
        D64[j] = P;
      }
      if (q == 0) {
#pragma unroll
        for (int j = 0; j < 4; ++j) redLds[wr][wc * 64 + j * 16 + lo] = D64[j];
      }
      asm volatile("s_waitcnt lgkmcnt(0)" ::: "memory");
      asm volatile("s_barrier" ::: "memory");
      if (t < 256) {
        const int s = t >> 7;                        // segment half (rows 0-127 / 128-255)
        const int col = t & 127;
        const int h = bn * 128 + col;
        const float a = avec[h];
        const float a2 = a * a, a4 = a2 * a2, a8 = a4 * a4, a16 = a8 * a8;
        const float a32 = a16 * a16, a64 = a32 * a32;
        float D = redLds[s * 2][col] * a64 + redLds[s * 2 + 1][col];
        Dred[(size_t)(bm * 2 + s) * H_DIM + h] = D + bproj[h] * gvec[h];
      }
#pragma unroll
      for (int i = 0; i < 4; i++)
#pragma unroll
        for (int j = 0; j < 4; j++) acc[i][j] = (f32x4){0.f, 0.f, 0.f, 0.f};
    }
    buf ^= 1;
  }
#undef STAGEB
#undef ALOAD
#undef AWRITE
}

// ---------------- prefix scan over k + hT (bf16 out) ----------------
__global__ __launch_bounds__(256) void state_kernel(const float* __restrict__ Dred,
                                                    const float* __restrict__ a128v,
                                                    unsigned short* __restrict__ hTbf) {
  int idx = blockIdx.x * 256 + threadIdx.x;  // b*1024 + h, 8192 total
  int b = idx >> 10, h = idx & 1023;
  const float* S = Dred + (size_t)b * KSUB * H_DIM + h;            // corr stream
  const float* Dd = Dred + (size_t)(B_DIM + b) * KSUB * H_DIM + h; // dec stream
  float A = a128v[h];
  float C = 0.f;
  for (int k = 0; k < KSUB; k++) {
    hTbf[((size_t)(b * KSUB + k)) * H_DIM + h] = f2bf(fmaf(A, C, Dd[(size_t)k * H_DIM]));
    C = fmaf(A, C, S[(size_t)k * H_DIM]);
  }
}

// ---------------- MFMA heads ----------------
// head1: y = silu(hT @ W_out + b_out)   M=256, N=1024, K=1024, out bf16
__global__ __launch_bounds__(256) void head1_kernel(const unsigned short* __restrict__ Abf,
                                                    const unsigned short* __restrict__ Bt,
                                                    const float* __restrict__ bias,
                                                    unsigned short* __restrict__ ybf) {
  __shared__ alignas(16) unsigned short As[128 * 32];
  __shared__ alignas(16) unsigned short Bs[128 * 32];
  const int t = threadIdx.x;
  const int lane = t & 63, wave = t >> 6;
  const int bm = blockIdx.x, bn = blockIdx.y;
  const int lo = lane & 15, q = lane >> 4;
  const int wm = wave & 1, wn = wave >> 1;

  f32x4 acc[4][4];
#pragma unroll
  for (int i = 0; i < 4; i++)
#pragma unroll
    for (int j = 0; j < 4; j++) acc[i][j] = (f32x4){0.f, 0.f, 0.f, 0.f};

  const int r0 = t >> 2;
  const int c0 = (t & 3) * 8;
  const unsigned short* Ag0 = Abf + ((size_t)bm * 128 + r0) * 1024 + c0;
  const unsigned short* Ag1 = Abf + ((size_t)bm * 128 + 64 + r0) * 1024 + c0;
  const unsigned short* Bg0 = Bt + ((size_t)bn * 128 + r0) * 1024 + c0;
  const unsigned short* Bg1 = Bt + ((size_t)bn * 128 + 64 + r0) * 1024 + c0;
  unsigned short* Al0 = &As[t * 8];
  unsigned short* Al1 = &As[(256 + t) * 8];
  unsigned short* Bl0 = &Bs[t * 8];
  unsigned short* Bl1 = &Bs[(256 + t) * 8];

  for (int kk = 0; kk < 1024; kk += 32) {
    async16(Ag0 + kk, Al0);
    async16(Ag1 + kk, Al1);
    async16(Bg0 + kk, Bl0);
    async16(Bg1 + kk, Bl1);
    __syncthreads();
    bf16x8 af[4], bv[4];
#pragma unroll
    for (int i = 0; i < 4; i++)
      af[i] = *(const bf16x8*)&As[(wm * 64 + i * 16 + lo) * 32 + q * 8];
#pragma unroll
    for (int j = 0; j < 4; j++)
      bv[j] = *(const bf16x8*)&Bs[(wn * 64 + j * 16 + lo) * 32 + q * 8];
#pragma unroll
    for (int i = 0; i < 4; i++)
#pragma unroll
      for (int j = 0; j < 4; j++)
        acc[i][j] = __builtin_amdgcn_mfma_f32_16x16x32_bf16(af[i], bv[j], acc[i][j], 0, 0, 0);
    __syncthreads();
  }

#pragma unroll
  for (int j = 0; j < 4; j++) {
    const int col = bn * 128 + wn * 64 + j * 16 + lo;
    const float bb = bias[col];
#pragma unroll
    for (int i = 0; i < 4; i++) {
#pragma unroll
      for (int r = 0; r < 4; r++) {
        const int row = bm * 128 + wm * 64 + i * 16 + q * 4 + r;
        float z = acc[i][j][r] + bb;
        float y = z / (1.f + expf(-z));
        ybf[(size_t)row * 1024 + col] = f2bf(y);
      }
    }
  }
}

// head2: [mu|lv] = y @ [W_mu|W_lv] + [b_mu|b_lv]   M=256, N=512, K=1024, out fp32
__global__ __launch_bounds__(256) void head2_kernel(const unsigned short* __restrict__ Abf,
                                                    const unsigned short* __restrict__ Bt,
                                                    const float* __restrict__ bmu,
                                                    const float* __restrict__ blv,
                                                    float* __restrict__ out) {
  __shared__ alignas(16) unsigned short As[128 * 32];
  __shared__ alignas(16) unsigned short Bs[128 * 32];
  const int t = threadIdx.x;
  const int lane = t & 63, wave = t >> 6;
  const int bm = blockIdx.x, bn = blockIdx.y;   // bn 0..3
  const int lo = lane & 15, q = lane >> 4;
  const int wm = wave & 1, wn = wave >> 1;

  f32x4 acc[4][4];
#pragma unroll
  for (int i = 0; i < 4; i++)
#pragma unroll
    for (int j = 0; j < 4; j++) acc[i][j] = (f32x4){0.f, 0.f, 0.f, 0.f};

  const int r0 = t >> 2;
  const int c0 = (t & 3) * 8;
  const unsigned short* Ag0 = Abf + ((size_t)bm * 128 + r0) * 1024 + c0;
  const unsigned short* Ag1 = Abf + ((size_t)bm * 128 + 64 + r0) * 1024 + c0;
  const unsigned short* Bg0 = Bt + ((size_t)bn * 128 + r0) * 1024 + c0;
  const unsigned short* Bg1 = Bt + ((size_t)bn * 128 + 64 + r0) * 1024 + c0;
  unsigned short* Al0 = &As[t * 8];
  unsigned short* Al1 = &As[(256 + t) * 8];
  unsigned short* Bl0 = &Bs[t * 8];
  unsigned short* Bl1 = &Bs[(256 + t) * 8];

  for (int kk = 0; kk < 1024; kk += 32) {
    async16(Ag0 + kk, Al0);
    async16(Ag1 + kk, Al1);
    async16(Bg0 + kk, Bl0);
    async16(Bg1 + kk, Bl1);
    __syncthreads();
    bf16x8 af[4], bv[4];
#pragma unroll
    for (int i = 0; i < 4; i++)
      af[i] = *(const bf16x8*)&As[(wm * 64 + i * 16 + lo) * 32 + q * 8];
#pragma unroll
    for (int j = 0; j < 4; j++)
      bv[j] = *(const bf16x8*)&Bs[(wn * 64 + j * 16 + lo) * 32 + q * 8];
#pragma unroll
    for (int i = 0; i < 4; i++)
#pragma unroll
      for (int j = 0; j < 4; j++)
        acc[i][j] = __builtin_amdgcn_mfma_f32_16x16x32_bf16(af[i], bv[j], acc[i][j], 0, 0, 0);
    __syncthreads();
  }

#pragma unroll
  for (int j = 0; j < 4; j++) {
    const int col = bn * 128 + wn * 64 + j * 16 + lo;   // 0..511
    const float bb = (col < 256) ? bmu[col] : blv[col - 256];
    float* dst = (col < 256) ? (out + col) : (out + 65536 + (col - 256));
#pragma unroll
    for (int i = 0; i < 4; i++) {
#pragma unroll
      for (int r = 0; r < 4; r++) {
        const int row = bm * 128 + wm * 64 + i * 16 + q * 4 + r;
        dst[(size_t)row * 256] = acc[i][j][r] + bb;
      }
    }
  }
}

// ---------------- launcher ----------------
extern "C" void kernel_launch(void* const* d_in, const int* in_sizes, int n_in,
                              void* d_out, int out_size, void* d_ws, size_t ws_size,
                              hipStream_t stream) {
  const float* decoder = (const float*)d_in[0];
  const float* targets = (const float*)d_in[1];
  const float* W_proj = (const float*)d_in[2];
  const float* b_proj = (const float*)d_in[3];
  const float* a_raw = (const float*)d_in[4];
  const float* W_out = (const float*)d_in[5];
  const float* b_out = (const float*)d_in[6];
  const float* W_mu = (const float*)d_in[7];
  const float* b_mu = (const float*)d_in[8];
  const float* W_lv = (const float*)d_in[9];
  const float* b_lv = (const float*)d_in[10];
  float* out = (float*)d_out;

  char* ws = (char*)d_ws;
  unsigned short* WT = (unsigned short*)(ws + 134217728);         // 2097152 B
  float* avec = (float*)(ws + 136314880);                         // 4096 B
  float* gvec = (float*)(ws + 136318976);                         // 4096 B
  float* a128v = (float*)(ws + 136323072);                        // 4096 B
  float* DredP = (float*)(ws + 136327168);                        // 2097152 B -> end 138424320
  // low workspace region:
  unsigned short* hTbf = (unsigned short*)ws;                     // 524288 B
  unsigned short* ybf = (unsigned short*)(ws + 524288);           // 524288 B
  unsigned short* WoutT = (unsigned short*)(ws + 1048576);        // 2097152 B
  unsigned short* WcatT = (unsigned short*)(ws + 3145728);        // 1048576 B

  prep_kernel<<<dim3(16, 16, 5), 256, 0, stream>>>(W_proj, a_raw, W_out, W_mu, W_lv,
                                                   WT, avec, gvec, a128v, WoutT, WcatT);
  gemm_seg_kernel<<<512, 512, 0, stream>>>(targets, decoder, WT, avec, gvec, b_proj, DredP);
  state_kernel<<<32, 256, 0, stream>>>(DredP, a128v, hTbf);
  head1_kernel<<<dim3(2, 8), 256, 0, stream>>>(hTbf, WoutT, b_out, ybf);
  head2_kernel<<<dim3(2, 4), 256, 0, stream>>>(ybf, WcatT, b_mu, b_lv, out);
}

// Round 9
// 426.482 us; speedup vs baseline: 1.5884x; 1.2450x over previous
//
#include <hip/hip_runtime.h>
#include <hip/hip_bf16.h>
#include <cstdint>
#include <cstddef>

#define B_DIM 8
#define L_DIM 4096
#define D_INN 1024
#define H_DIM 1024
#define LATENTD 256
#define SEGLEN 128
#define KSUB 32
#define M_HALF (B_DIM * L_DIM)      // 32768
#define M_TOTAL (2 * M_HALF)        // 65536

typedef __attribute__((ext_vector_type(8))) short bf16x8;
typedef __attribute__((ext_vector_type(4))) float f32x4;

static __device__ __forceinline__ unsigned short f2bf(float x) {
  __hip_bfloat16 b = __float2bfloat16(x);
  return __builtin_bit_cast(unsigned short, b);
}

static __device__ __forceinline__ void async16(const unsigned short* g, unsigned short* l) {
  __builtin_amdgcn_global_load_lds(
      (const __attribute__((address_space(1))) unsigned int*)g,
      (__attribute__((address_space(3))) unsigned int*)l,
      16, 0, 0);
}

// ---------------- combined prep kernel (R4-verified, unchanged) ----------------
__global__ __launch_bounds__(256) void prep_kernel(const float* __restrict__ W_proj,
                                                   const float* __restrict__ a_raw,
                                                   const float* __restrict__ Wo,
                                                   const float* __restrict__ Wm,
                                                   const float* __restrict__ Wl,
                                                   unsigned short* __restrict__ WT,
                                                   float* __restrict__ avec,
                                                   float* __restrict__ gvec,
                                                   float* __restrict__ a128v,
                                                   unsigned short* __restrict__ WoutT,
                                                   unsigned short* __restrict__ WcatT) {
  const int z = blockIdx.z;
  if (z == 4) {
    if (blockIdx.y != 0 || blockIdx.x >= 4) return;
    int h = blockIdx.x * 256 + threadIdx.x;
    float a = 1.f / (1.f + expf(-a_raw[h]));
    float p = 1.f, g = 0.f;
    for (int j = 0; j < SEGLEN; j++) { g += p; p *= a; }
    avec[h] = a; gvec[h] = g; a128v[h] = p;   // p = a^128
    return;
  }
  __shared__ float tile[64][65];
  const float* src; unsigned short* dst; int N; int rowoff;
  if (z == 0)      { src = W_proj; dst = WT;    N = 1024; rowoff = 0; }
  else if (z == 1) { src = Wo;     dst = WoutT; N = 1024; rowoff = 0; }
  else if (z == 2) { src = Wm;     dst = WcatT; N = 256;  rowoff = 0; }
  else             { src = Wl;     dst = WcatT; N = 256;  rowoff = 256; }
  int k0 = blockIdx.x * 64, n0 = blockIdx.y * 64;
  if (n0 >= N) return;
  for (int i = threadIdx.x; i < 64 * 64; i += 256) {
    int kk = i >> 6, nn = i & 63;
    tile[kk][nn] = src[(size_t)(k0 + kk) * N + n0 + nn];
  }
  __syncthreads();
  for (int i = threadIdx.x; i < 64 * 64; i += 256) {
    int nn = i >> 6, kk = i & 63;
    dst[(size_t)(rowoff + n0 + nn) * 1024 + k0 + kk] = f2bf(tile[kk][nn]);
  }
}

// ---------------- main GEMM + segment decay reduction (persistent) ----------
// EXACT R6 structure (best measured: 177us, MfmaUtil 33%) restored after the
// R7 (counted-lgkm spill) and R8 (BK=32 sync-quantum halving) regressions.
// Deltas vs R6, both bounded:
//  (1) __launch_bounds__(512,2): true occupancy target (2 waves/SIMD at
//      128KB LDS) -> allocator may use up to 256 VGPR instead of spilling.
//  (2) b1 reads (4 frags, +16 VGPR live) hoisted above MFMA0: compiler waits
//      lgkmcnt(4) (a0/b0 only) before the first MFMA; b1 retires under the
//      MFMA0 cluster. a1 reads stay after MFMA0 (as in R6).
// All else identical: persistent 256 blocks (1/CU), 4 items x 16 K-tiles as
// one continuous pipeline; A fp32 reg-staged (full-tile prefetch distance),
// cvt + swizzled ds_write; B via global_load_lds w/ pre-swizzled source;
// counted vmcnt(4) at tile end.

__global__ __launch_bounds__(512, 2) void gemm_seg_kernel(const float* __restrict__ Atgt,
                                                          const float* __restrict__ Adec,
                                                          const unsigned short* __restrict__ WT,
                                                          const float* __restrict__ avec,
                                                          const float* __restrict__ gvec,
                                                          const float* __restrict__ bproj,
                                                          float* __restrict__ Dred) {
  __shared__ alignas(16) unsigned short lds[65536];  // 128 KiB: A [0,32768), B [32768,65536)

  const int t = threadIdx.x;          // 0..511
  const int lane = t & 63;
  const int wave = t >> 6;            // 0..7
  const int wr = wave >> 2;           // 0..1  M-half (= segment within tile)
  const int wc = wave & 3;            // 0..3  N-quarter
  const int lo = lane & 15;
  const int q = lane >> 4;

  const int bid = blockIdx.x;         // 0..255
  const int bn = (bid >> 3) & 3;                          // fixed per block
  const int bm0 = ((bid & 7) * 128 + (bid >> 3)) >> 2;    // item 0's bm; bm(it)=bm0+8it

  // ---- B staging (global_load_lds, pre-swizzled source; depends on kk only) ----
  const int tr = t >> 3;                                  // row-within-64
  const int csw = (((t & 7) ^ (tr & 7)) * 8);             // pre-swizzled col (shorts)
  const unsigned short* Bsrc = WT + ((size_t)(bn * 256 + tr)) * 1024 + csw;
  unsigned short* ldsB = lds + 32768 + t * 8;

#define STAGEB(buf_, gt_)                                                          \
  {                                                                                \
    _Pragma("unroll")                                                              \
    for (int hl = 0; hl < 4; ++hl) {                                               \
      const int half_ = hl >> 1, l_ = hl & 1;                                      \
      async16(Bsrc + (size_t)(half_ * 128 + l_ * 64) * 1024 + ((gt_) & 15) * 64,   \
              ldsB + (buf_) * 16384 + half_ * 8192 + l_ * 4096);                   \
    }                                                                              \
  }

  // ---- A reg-staging (fused fp32 read + convert) ----
  const float* Afp = ((bm0 < 128) ? Atgt : Adec) + ((size_t)(bm0 & 127)) * 256 * 1024;
  const float* Ath = Afp + ((size_t)(t >> 4)) * 1024 + (t & 15) * 4;
  const int awr_swz = (((((t & 15) >> 1)) ^ ((t >> 4) & 7)) * 8) + (t & 1) * 4;
  unsigned short* ldsAw = lds + ((t >> 4) * 64) + awr_swz;

  float4 fA[8];

#define ALOAD(gt_)                                                                 \
  {                                                                                \
    _Pragma("unroll")                                                              \
    for (int i_ = 0; i_ < 8; ++i_)                                                 \
      fA[i_] = *(const float4*)(Ath + (size_t)i_ * 32768 +                         \
                                (size_t)((gt_) >> 4) * 2097152 + ((gt_) & 15) * 64); \
  }

#define AWRITE(buf_)                                                               \
  {                                                                                \
    _Pragma("unroll")                                                              \
    for (int i_ = 0; i_ < 8; ++i_) {                                               \
      ushort4 o_;                                                                  \
      o_.x = f2bf(fA[i_].x); o_.y = f2bf(fA[i_].y);                                \
      o_.z = f2bf(fA[i_].z); o_.w = f2bf(fA[i_].w);                                \
      *(ushort4*)(ldsAw + (buf_) * 16384 + i_ * 2048) = o_;                        \
    }                                                                              \
  }

  // ---- ds_read addressing (swizzled; unchanged from verified R2-R6) ----
  const unsigned short* ArdB = lds + (size_t)(wr * 128 + lo) * 64;
  const unsigned short* BrdB = lds + 32768 + (size_t)(wc * 64 + lo) * 64;
  const int ch0 = ((q ^ (lo & 7)) * 8);        // k-slice 0 chunk (shorts)
  const int ch1 = (((4 + q) ^ (lo & 7)) * 8);  // k-slice 1 chunk (shorts)

  f32x4 acc[8][4];
#pragma unroll
  for (int i = 0; i < 8; i++)
#pragma unroll
    for (int j = 0; j < 4; j++) acc[i][j] = (f32x4){0.f, 0.f, 0.f, 0.f};

  // ---- prologue (once per block): buf0<-gt0, buf1<-gt1, regs<-gt2 in flight ----
  ALOAD(0);
  __builtin_amdgcn_sched_barrier(0);
  STAGEB(0, 0);
  STAGEB(1, 1);
  __builtin_amdgcn_sched_barrier(0);
  asm volatile("s_waitcnt vmcnt(8)" ::: "memory");   // ALOAD(0) landed (8 newest = B asyncs)
  AWRITE(0);
  ALOAD(1);
  __builtin_amdgcn_sched_barrier(0);
  asm volatile("s_waitcnt vmcnt(0)" ::: "memory");   // ALOAD(1) + all B landed
  AWRITE(1);
  ALOAD(2);                                          // flies across gt 0
  __builtin_amdgcn_sched_barrier(0);
  asm volatile("s_waitcnt lgkmcnt(0)" ::: "memory");
  __builtin_amdgcn_sched_barrier(0);

  int buf = 0;
  for (int gt = 0; gt < 64; ++gt) {                  // 4 items x 16 K-tiles, continuous
    if (gt == 63) asm volatile("s_waitcnt vmcnt(0)" ::: "memory");
    asm volatile("s_barrier" ::: "memory");          // top: publish buf
    __builtin_amdgcn_sched_barrier(0);

    const unsigned short* Ab = ArdB + buf * 16384;
    const unsigned short* Bb = BrdB + buf * 16384;

    // b0/a0 reads + b1 hoisted (delta 2): MFMA0 waits only on a0/b0
    bf16x8 a0[8], b0[4], b1[4];
#pragma unroll
    for (int j = 0; j < 4; j++) b0[j] = *(const bf16x8*)&Bb[j * 1024 + ch0];
#pragma unroll
    for (int i = 0; i < 8; i++) a0[i] = *(const bf16x8*)&Ab[i * 1024 + ch0];
#pragma unroll
    for (int j = 0; j < 4; j++) b1[j] = *(const bf16x8*)&Bb[j * 1024 + ch1];

#pragma unroll
    for (int i = 0; i < 8; i++)
#pragma unroll
      for (int j = 0; j < 4; j++)
        acc[i][j] = __builtin_amdgcn_mfma_f32_16x16x32_bf16(a0[i], b0[j], acc[i][j], 0, 0, 0);

    bf16x8 a1[8];
#pragma unroll
    for (int i = 0; i < 8; i++) a1[i] = *(const bf16x8*)&Ab[i * 1024 + ch1];

    // all LDS reads of this buffer done (per-wave), then workgroup-wide
    asm volatile("s_waitcnt lgkmcnt(0)" ::: "memory");
    __builtin_amdgcn_sched_barrier(0);
    asm volatile("s_barrier" ::: "memory");

    if (gt < 62) STAGEB(buf, gt + 2);                // clobber-safe: all past buf reads

    __builtin_amdgcn_s_setprio(1);
#pragma unroll
    for (int i = 0; i < 8; i++)
#pragma unroll
      for (int j = 0; j < 4; j++)
        acc[i][j] = __builtin_amdgcn_mfma_f32_16x16x32_bf16(a1[i], b1[j], acc[i][j], 0, 0, 0);
    __builtin_amdgcn_s_setprio(0);
    __builtin_amdgcn_sched_barrier(0);

    if (gt < 62) {
      // outstanding (oldest->newest): [STAGEB(gt+1)] [ALOAD(gt+2) x8] [STAGEB(gt+2) x4]
      // vmcnt(4): leaves only the 4 newest B-asyncs in flight.
      asm volatile("s_waitcnt vmcnt(4)" ::: "memory");
      __builtin_amdgcn_sched_barrier(0);
      AWRITE(buf);                   // cvt + conflict-free swizzled ds_write
      if (gt < 61) ALOAD(gt + 3);    // regs free -> next A flies a FULL tile
      __builtin_amdgcn_sched_barrier(0);
      asm volatile("s_waitcnt lgkmcnt(0)" ::: "memory");  // AWRITE visible before top barrier
      __builtin_amdgcn_sched_barrier(0);
    }

    // ---- per-item epilogue at gt&15==15: Horner decay reduce, store, reset ----
    if ((gt & 15) == 15) {
      const int itv = gt >> 4;
      const int seg = (bm0 + 8 * itv) * 2 + wr;
#pragma unroll
      for (int j = 0; j < 4; ++j) {
        const int h = bn * 256 + wc * 64 + j * 16 + lo;
        const float a = avec[h];
        const float a2 = a * a, a4 = a2 * a2, a8 = a4 * a4, a16 = a8 * a8;
        float P = 0.f;
#pragma unroll
        for (int i = 0; i < 8; ++i) {
          f32x4 u = acc[i][j];
          float vi = ((u.x * a + u.y) * a + u.z) * a + u.w;
          P = P * a16 + vi;
        }
        const float qf = (q == 3) ? 1.f : ((q == 2) ? a4 : ((q == 1) ? a8 : a8 * a4));
        P *= qf;
        P += __shfl_xor(P, 16);
        P += __shfl_xor(P, 32);
        if (q == 0)
          Dred[(size_t)seg * H_DIM + h] = P + bproj[h] * gvec[h];
      }
#pragma unroll
      for (int i = 0; i < 8; i++)
#pragma unroll
        for (int j = 0; j < 4; j++) acc[i][j] = (f32x4){0.f, 0.f, 0.f, 0.f};
    }
    buf ^= 1;
  }
#undef STAGEB
#undef ALOAD
#undef AWRITE
}

// ---------------- prefix scan over k + hT (bf16 out) ----------------
__global__ __launch_bounds__(256) void state_kernel(const float* __restrict__ Dred,
                                                    const float* __restrict__ a128v,
                                                    unsigned short* __restrict__ hTbf) {
  int idx = blockIdx.x * 256 + threadIdx.x;  // b*1024 + h, 8192 total
  int b = idx >> 10, h = idx & 1023;
  const float* S = Dred + (size_t)b * KSUB * H_DIM + h;            // corr stream
  const float* Dd = Dred + (size_t)(B_DIM + b) * KSUB * H_DIM + h; // dec stream
  float A = a128v[h];
  float C = 0.f;
  for (int k = 0; k < KSUB; k++) {
    hTbf[((size_t)(b * KSUB + k)) * H_DIM + h] = f2bf(fmaf(A, C, Dd[(size_t)k * H_DIM]));
    C = fmaf(A, C, S[(size_t)k * H_DIM]);
  }
}

// ---------------- MFMA heads ----------------
// head1: y = silu(hT @ W_out + b_out)   M=256, N=1024, K=1024, out bf16
__global__ __launch_bounds__(256) void head1_kernel(const unsigned short* __restrict__ Abf,
                                                    const unsigned short* __restrict__ Bt,
                                                    const float* __restrict__ bias,
                                                    unsigned short* __restrict__ ybf) {
  __shared__ alignas(16) unsigned short As[128 * 32];
  __shared__ alignas(16) unsigned short Bs[128 * 32];
  const int t = threadIdx.x;
  const int lane = t & 63, wave = t >> 6;
  const int bm = blockIdx.x, bn = blockIdx.y;
  const int lo = lane & 15, q = lane >> 4;
  const int wm = wave & 1, wn = wave >> 1;

  f32x4 acc[4][4];
#pragma unroll
  for (int i = 0; i < 4; i++)
#pragma unroll
    for (int j = 0; j < 4; j++) acc[i][j] = (f32x4){0.f, 0.f, 0.f, 0.f};

  const int r0 = t >> 2;
  const int c0 = (t & 3) * 8;
  const unsigned short* Ag0 = Abf + ((size_t)bm * 128 + r0) * 1024 + c0;
  const unsigned short* Ag1 = Abf + ((size_t)bm * 128 + 64 + r0) * 1024 + c0;
  const unsigned short* Bg0 = Bt + ((size_t)bn * 128 + r0) * 1024 + c0;
  const unsigned short* Bg1 = Bt + ((size_t)bn * 128 + 64 + r0) * 1024 + c0;
  unsigned short* Al0 = &As[t * 8];
  unsigned short* Al1 = &As[(256 + t) * 8];
  unsigned short* Bl0 = &Bs[t * 8];
  unsigned short* Bl1 = &Bs[(256 + t) * 8];

  for (int kk = 0; kk < 1024; kk += 32) {
    async16(Ag0 + kk, Al0);
    async16(Ag1 + kk, Al1);
    async16(Bg0 + kk, Bl0);
    async16(Bg1 + kk, Bl1);
    __syncthreads();
    bf16x8 af[4], bv[4];
#pragma unroll
    for (int i = 0; i < 4; i++)
      af[i] = *(const bf16x8*)&As[(wm * 64 + i * 16 + lo) * 32 + q * 8];
#pragma unroll
    for (int j = 0; j < 4; j++)
      bv[j] = *(const bf16x8*)&Bs[(wn * 64 + j * 16 + lo) * 32 + q * 8];
#pragma unroll
    for (int i = 0; i < 4; i++)
#pragma unroll
      for (int j = 0; j < 4; j++)
        acc[i][j] = __builtin_amdgcn_mfma_f32_16x16x32_bf16(af[i], bv[j], acc[i][j], 0, 0, 0);
    __syncthreads();
  }

#pragma unroll
  for (int j = 0; j < 4; j++) {
    const int col = bn * 128 + wn * 64 + j * 16 + lo;
    const float bb = bias[col];
#pragma unroll
    for (int i = 0; i < 4; i++) {
#pragma unroll
      for (int r = 0; r < 4; r++) {
        const int row = bm * 128 + wm * 64 + i * 16 + q * 4 + r;
        float z = acc[i][j][r] + bb;
        float y = z / (1.f + expf(-z));
        ybf[(size_t)row * 1024 + col] = f2bf(y);
      }
    }
  }
}

// head2: [mu|lv] = y @ [W_mu|W_lv] + [b_mu|b_lv]   M=256, N=512, K=1024, out fp32
__global__ __launch_bounds__(256) void head2_kernel(const unsigned short* __restrict__ Abf,
                                                    const unsigned short* __restrict__ Bt,
                                                    const float* __restrict__ bmu,
                                                    const float* __restrict__ blv,
                                                    float* __restrict__ out) {
  __shared__ alignas(16) unsigned short As[128 * 32];
  __shared__ alignas(16) unsigned short Bs[128 * 32];
  const int t = threadIdx.x;
  const int lane = t & 63, wave = t >> 6;
  const int bm = blockIdx.x, bn = blockIdx.y;   // bn 0..3
  const int lo = lane & 15, q = lane >> 4;
  const int wm = wave & 1, wn = wave >> 1;

  f32x4 acc[4][4];
#pragma unroll
  for (int i = 0; i < 4; i++)
#pragma unroll
    for (int j = 0; j < 4; j++) acc[i][j] = (f32x4){0.f, 0.f, 0.f, 0.f};

  const int r0 = t >> 2;
  const int c0 = (t & 3) * 8;
  const unsigned short* Ag0 = Abf + ((size_t)bm * 128 + r0) * 1024 + c0;
  const unsigned short* Ag1 = Abf + ((size_t)bm * 128 + 64 + r0) * 1024 + c0;
  const unsigned short* Bg0 = Bt + ((size_t)bn * 128 + r0) * 1024 + c0;
  const unsigned short* Bg1 = Bt + ((size_t)bn * 128 + 64 + r0) * 1024 + c0;
  unsigned short* Al0 = &As[t * 8];
  unsigned short* Al1 = &As[(256 + t) * 8];
  unsigned short* Bl0 = &Bs[t * 8];
  unsigned short* Bl1 = &Bs[(256 + t) * 8];

  for (int kk = 0; kk < 1024; kk += 32) {
    async16(Ag0 + kk, Al0);
    async16(Ag1 + kk, Al1);
    async16(Bg0 + kk, Bl0);
    async16(Bg1 + kk, Bl1);
    __syncthreads();
    bf16x8 af[4], bv[4];
#pragma unroll
    for (int i = 0; i < 4; i++)
      af[i] = *(const bf16x8*)&As[(wm * 64 + i * 16 + lo) * 32 + q * 8];
#pragma unroll
    for (int j = 0; j < 4; j++)
      bv[j] = *(const bf16x8*)&Bs[(wn * 64 + j * 16 + lo) * 32 + q * 8];
#pragma unroll
    for (int i = 0; i < 4; i++)
#pragma unroll
      for (int j = 0; j < 4; j++)
        acc[i][j] = __builtin_amdgcn_mfma_f32_16x16x32_bf16(af[i], bv[j], acc[i][j], 0, 0, 0);
    __syncthreads();
  }

#pragma unroll
  for (int j = 0; j < 4; j++) {
    const int col = bn * 128 + wn * 64 + j * 16 + lo;   // 0..511
    const float bb = (col < 256) ? bmu[col] : blv[col - 256];
    float* dst = (col < 256) ? (out + col) : (out + 65536 + (col - 256));
#pragma unroll
    for (int i = 0; i < 4; i++) {
#pragma unroll
      for (int r = 0; r < 4; r++) {
        const int row = bm * 128 + wm * 64 + i * 16 + q * 4 + r;
        dst[(size_t)row * 256] = acc[i][j][r] + bb;
      }
    }
  }
}

// ---------------- launcher ----------------
extern "C" void kernel_launch(void* const* d_in, const int* in_sizes, int n_in,
                              void* d_out, int out_size, void* d_ws, size_t ws_size,
                              hipStream_t stream) {
  const float* decoder = (const float*)d_in[0];
  const float* targets = (const float*)d_in[1];
  const float* W_proj = (const float*)d_in[2];
  const float* b_proj = (const float*)d_in[3];
  const float* a_raw = (const float*)d_in[4];
  const float* W_out = (const float*)d_in[5];
  const float* b_out = (const float*)d_in[6];
  const float* W_mu = (const float*)d_in[7];
  const float* b_mu = (const float*)d_in[8];
  const float* W_lv = (const float*)d_in[9];
  const float* b_lv = (const float*)d_in[10];
  float* out = (float*)d_out;

  char* ws = (char*)d_ws;
  unsigned short* WT = (unsigned short*)(ws + 134217728);         // 2097152 B
  float* avec = (float*)(ws + 136314880);                         // 4096 B
  float* gvec = (float*)(ws + 136318976);                         // 4096 B
  float* a128v = (float*)(ws + 136323072);                        // 4096 B
  float* DredP = (float*)(ws + 136327168);                        // 2097152 B -> end 138424320
  // low workspace region:
  unsigned short* hTbf = (unsigned short*)ws;                     // 524288 B
  unsigned short* ybf = (unsigned short*)(ws + 524288);           // 524288 B
  unsigned short* WoutT = (unsigned short*)(ws + 1048576);        // 2097152 B
  unsigned short* WcatT = (unsigned short*)(ws + 3145728);        // 1048576 B

  prep_kernel<<<dim3(16, 16, 5), 256, 0, stream>>>(W_proj, a_raw, W_out, W_mu, W_lv,
                                                   WT, avec, gvec, a128v, WoutT, WcatT);
  gemm_seg_kernel<<<256, 512, 0, stream>>>(targets, decoder, WT, avec, gvec, b_proj, DredP);
  state_kernel<<<32, 256, 0, stream>>>(DredP, a128v, hTbf);
  head1_kernel<<<dim3(2, 8), 256, 0, stream>>>(hTbf, WoutT, b_out, ybf);
  head2_kernel<<<dim3(2, 4), 256, 0, stream>>>(ybf, WcatT, b_mu, b_lv, out);
}

// Round 10
// 416.188 us; speedup vs baseline: 1.6277x; 1.0247x over previous
//
#include <hip/hip_runtime.h>
#include <hip/hip_bf16.h>
#include <cstdint>
#include <cstddef>

#define B_DIM 8
#define L_DIM 4096
#define D_INN 1024
#define H_DIM 1024
#define LATENTD 256
#define SEGLEN 128
#define KSUB 32
#define M_HALF (B_DIM * L_DIM)      // 32768
#define M_TOTAL (2 * M_HALF)        // 65536

typedef __attribute__((ext_vector_type(8))) short bf16x8;
typedef __attribute__((ext_vector_type(4))) float f32x4;

static __device__ __forceinline__ unsigned short f2bf(float x) {
  __hip_bfloat16 b = __float2bfloat16(x);
  return __builtin_bit_cast(unsigned short, b);
}

static __device__ __forceinline__ void async16(const unsigned short* g, unsigned short* l) {
  __builtin_amdgcn_global_load_lds(
      (const __attribute__((address_space(1))) unsigned int*)g,
      (__attribute__((address_space(3))) unsigned int*)l,
      16, 0, 0);
}

// ---------------- combined prep kernel (R4-verified, unchanged) ----------------
__global__ __launch_bounds__(256) void prep_kernel(const float* __restrict__ W_proj,
                                                   const float* __restrict__ a_raw,
                                                   const float* __restrict__ Wo,
                                                   const float* __restrict__ Wm,
                                                   const float* __restrict__ Wl,
                                                   unsigned short* __restrict__ WT,
                                                   float* __restrict__ avec,
                                                   float* __restrict__ gvec,
                                                   float* __restrict__ a128v,
                                                   unsigned short* __restrict__ WoutT,
                                                   unsigned short* __restrict__ WcatT) {
  const int z = blockIdx.z;
  if (z == 4) {
    if (blockIdx.y != 0 || blockIdx.x >= 4) return;
    int h = blockIdx.x * 256 + threadIdx.x;
    float a = 1.f / (1.f + expf(-a_raw[h]));
    float p = 1.f, g = 0.f;
    for (int j = 0; j < SEGLEN; j++) { g += p; p *= a; }
    avec[h] = a; gvec[h] = g; a128v[h] = p;   // p = a^128
    return;
  }
  __shared__ float tile[64][65];
  const float* src; unsigned short* dst; int N; int rowoff;
  if (z == 0)      { src = W_proj; dst = WT;    N = 1024; rowoff = 0; }
  else if (z == 1) { src = Wo;     dst = WoutT; N = 1024; rowoff = 0; }
  else if (z == 2) { src = Wm;     dst = WcatT; N = 256;  rowoff = 0; }
  else             { src = Wl;     dst = WcatT; N = 256;  rowoff = 256; }
  int k0 = blockIdx.x * 64, n0 = blockIdx.y * 64;
  if (n0 >= N) return;
  for (int i = threadIdx.x; i < 64 * 64; i += 256) {
    int kk = i >> 6, nn = i & 63;
    tile[kk][nn] = src[(size_t)(k0 + kk) * N + n0 + nn];
  }
  __syncthreads();
  for (int i = threadIdx.x; i < 64 * 64; i += 256) {
    int nn = i >> 6, kk = i & 63;
    dst[(size_t)(rowoff + n0 + nn) * 1024 + k0 + kk] = f2bf(tile[kk][nn]);
  }
}

// ---------------- main GEMM + segment decay reduction (persistent) ----------
// EXACT R6 kernel (best measured: 176.7us gemm / 424.9us pipeline).
// R9's two deltas reverted: plain __launch_bounds__(512) (the (512,2) hint
// changed nothing: allocator pins 128 VGPR), and NO b1 hoist (it extended
// fragment lifetimes across MFMA0 and cost ~5us).
// Structure: persistent 256 blocks (1/CU); 4 items x 16 K-tiles as one
// continuous 64-tile pipeline (prologue once, dbuf never drains between
// items). A fp32 reg-staged with FULL-TILE prefetch distance (ALOAD(t+3)
// issued right after AWRITE frees regs); B via global_load_lds with
// pre-swizzled source; counted vmcnt(4) at tile end drains exactly A(t+2)+
// B(t+1), keeps the 4 newest B-asyncs flying. XOR swizzle keeps both the
// ds_write and ds_read_b128 paths bank-conflict-free (measured 0).

__global__ __launch_bounds__(512) void gemm_seg_kernel(const float* __restrict__ Atgt,
                                                       const float* __restrict__ Adec,
                                                       const unsigned short* __restrict__ WT,
                                                       const float* __restrict__ avec,
                                                       const float* __restrict__ gvec,
                                                       const float* __restrict__ bproj,
                                                       float* __restrict__ Dred) {
  __shared__ alignas(16) unsigned short lds[65536];  // 128 KiB: A [0,32768), B [32768,65536)

  const int t = threadIdx.x;          // 0..511
  const int lane = t & 63;
  const int wave = t >> 6;            // 0..7
  const int wr = wave >> 2;           // 0..1  M-half (= segment within tile)
  const int wc = wave & 3;            // 0..3  N-quarter
  const int lo = lane & 15;
  const int q = lane >> 4;

  const int bid = blockIdx.x;         // 0..255
  const int bn = (bid >> 3) & 3;                          // fixed per block
  const int bm0 = ((bid & 7) * 128 + (bid >> 3)) >> 2;    // item 0's bm; bm(it)=bm0+8it

  // ---- B staging (global_load_lds, pre-swizzled source; depends on kk only) ----
  const int tr = t >> 3;                                  // row-within-64
  const int csw = (((t & 7) ^ (tr & 7)) * 8);             // pre-swizzled col (shorts)
  const unsigned short* Bsrc = WT + ((size_t)(bn * 256 + tr)) * 1024 + csw;
  unsigned short* ldsB = lds + 32768 + t * 8;

#define STAGEB(buf_, gt_)                                                          \
  {                                                                                \
    _Pragma("unroll")                                                              \
    for (int hl = 0; hl < 4; ++hl) {                                               \
      const int half_ = hl >> 1, l_ = hl & 1;                                      \
      async16(Bsrc + (size_t)(half_ * 128 + l_ * 64) * 1024 + ((gt_) & 15) * 64,   \
              ldsB + (buf_) * 16384 + half_ * 8192 + l_ * 4096);                   \
    }                                                                              \
  }

  // ---- A reg-staging (fused fp32 read + convert) ----
  const float* Afp = ((bm0 < 128) ? Atgt : Adec) + ((size_t)(bm0 & 127)) * 256 * 1024;
  const float* Ath = Afp + ((size_t)(t >> 4)) * 1024 + (t & 15) * 4;
  const int awr_swz = (((((t & 15) >> 1)) ^ ((t >> 4) & 7)) * 8) + (t & 1) * 4;
  unsigned short* ldsAw = lds + ((t >> 4) * 64) + awr_swz;

  float4 fA[8];

#define ALOAD(gt_)                                                                 \
  {                                                                                \
    _Pragma("unroll")                                                              \
    for (int i_ = 0; i_ < 8; ++i_)                                                 \
      fA[i_] = *(const float4*)(Ath + (size_t)i_ * 32768 +                         \
                                (size_t)((gt_) >> 4) * 2097152 + ((gt_) & 15) * 64); \
  }

#define AWRITE(buf_)                                                               \
  {                                                                                \
    _Pragma("unroll")                                                              \
    for (int i_ = 0; i_ < 8; ++i_) {                                               \
      ushort4 o_;                                                                  \
      o_.x = f2bf(fA[i_].x); o_.y = f2bf(fA[i_].y);                                \
      o_.z = f2bf(fA[i_].z); o_.w = f2bf(fA[i_].w);                                \
      *(ushort4*)(ldsAw + (buf_) * 16384 + i_ * 2048) = o_;                        \
    }                                                                              \
  }

  // ---- ds_read addressing (swizzled; unchanged from verified R2-R6) ----
  const unsigned short* ArdB = lds + (size_t)(wr * 128 + lo) * 64;
  const unsigned short* BrdB = lds + 32768 + (size_t)(wc * 64 + lo) * 64;
  const int ch0 = ((q ^ (lo & 7)) * 8);        // k-slice 0 chunk (shorts)
  const int ch1 = (((4 + q) ^ (lo & 7)) * 8);  // k-slice 1 chunk (shorts)

  f32x4 acc[8][4];
#pragma unroll
  for (int i = 0; i < 8; i++)
#pragma unroll
    for (int j = 0; j < 4; j++) acc[i][j] = (f32x4){0.f, 0.f, 0.f, 0.f};

  // ---- prologue (once per block): buf0<-gt0, buf1<-gt1, regs<-gt2 in flight ----
  ALOAD(0);
  __builtin_amdgcn_sched_barrier(0);
  STAGEB(0, 0);
  STAGEB(1, 1);
  __builtin_amdgcn_sched_barrier(0);
  asm volatile("s_waitcnt vmcnt(8)" ::: "memory");   // ALOAD(0) landed (8 newest = B asyncs)
  AWRITE(0);
  ALOAD(1);
  __builtin_amdgcn_sched_barrier(0);
  asm volatile("s_waitcnt vmcnt(0)" ::: "memory");   // ALOAD(1) + all B landed
  AWRITE(1);
  ALOAD(2);                                          // flies across gt 0
  __builtin_amdgcn_sched_barrier(0);
  asm volatile("s_waitcnt lgkmcnt(0)" ::: "memory");
  __builtin_amdgcn_sched_barrier(0);

  int buf = 0;
  for (int gt = 0; gt < 64; ++gt) {                  // 4 items x 16 K-tiles, continuous
    if (gt == 63) asm volatile("s_waitcnt vmcnt(0)" ::: "memory");
    asm volatile("s_barrier" ::: "memory");          // top: publish buf
    __builtin_amdgcn_sched_barrier(0);

    const unsigned short* Ab = ArdB + buf * 16384;
    const unsigned short* Bb = BrdB + buf * 16384;

    bf16x8 a0[8], b0[4];
#pragma unroll
    for (int i = 0; i < 8; i++) a0[i] = *(const bf16x8*)&Ab[i * 1024 + ch0];
#pragma unroll
    for (int j = 0; j < 4; j++) b0[j] = *(const bf16x8*)&Bb[j * 1024 + ch0];
#pragma unroll
    for (int i = 0; i < 8; i++)
#pragma unroll
      for (int j = 0; j < 4; j++)
        acc[i][j] = __builtin_amdgcn_mfma_f32_16x16x32_bf16(a0[i], b0[j], acc[i][j], 0, 0, 0);

    bf16x8 a1[8], b1[4];
#pragma unroll
    for (int i = 0; i < 8; i++) a1[i] = *(const bf16x8*)&Ab[i * 1024 + ch1];
#pragma unroll
    for (int j = 0; j < 4; j++) b1[j] = *(const bf16x8*)&Bb[j * 1024 + ch1];

    // all LDS reads of this buffer done (per-wave), then workgroup-wide
    asm volatile("s_waitcnt lgkmcnt(0)" ::: "memory");
    __builtin_amdgcn_sched_barrier(0);
    asm volatile("s_barrier" ::: "memory");

    if (gt < 62) STAGEB(buf, gt + 2);                // clobber-safe: all past buf reads

    __builtin_amdgcn_s_setprio(1);
#pragma unroll
    for (int i = 0; i < 8; i++)
#pragma unroll
      for (int j = 0; j < 4; j++)
        acc[i][j] = __builtin_amdgcn_mfma_f32_16x16x32_bf16(a1[i], b1[j], acc[i][j], 0, 0, 0);
    __builtin_amdgcn_s_setprio(0);
    __builtin_amdgcn_sched_barrier(0);

    if (gt < 62) {
      // outstanding (oldest->newest): [STAGEB(gt+1)] [ALOAD(gt+2) x8] [STAGEB(gt+2) x4]
      // vmcnt(4): leaves only the 4 newest B-asyncs in flight.
      asm volatile("s_waitcnt vmcnt(4)" ::: "memory");
      __builtin_amdgcn_sched_barrier(0);
      AWRITE(buf);                   // cvt + conflict-free swizzled ds_write
      if (gt < 61) ALOAD(gt + 3);    // regs free -> next A flies a FULL tile
      __builtin_amdgcn_sched_barrier(0);
      asm volatile("s_waitcnt lgkmcnt(0)" ::: "memory");  // AWRITE visible before top barrier
      __builtin_amdgcn_sched_barrier(0);
    }

    // ---- per-item epilogue at gt&15==15: Horner decay reduce, store, reset ----
    if ((gt & 15) == 15) {
      const int itv = gt >> 4;
      const int seg = (bm0 + 8 * itv) * 2 + wr;
#pragma unroll
      for (int j = 0; j < 4; ++j) {
        const int h = bn * 256 + wc * 64 + j * 16 + lo;
        const float a = avec[h];
        const float a2 = a * a, a4 = a2 * a2, a8 = a4 * a4, a16 = a8 * a8;
        float P = 0.f;
#pragma unroll
        for (int i = 0; i < 8; ++i) {
          f32x4 u = acc[i][j];
          float vi = ((u.x * a + u.y) * a + u.z) * a + u.w;
          P = P * a16 + vi;
        }
        const float qf = (q == 3) ? 1.f : ((q == 2) ? a4 : ((q == 1) ? a8 : a8 * a4));
        P *= qf;
        P += __shfl_xor(P, 16);
        P += __shfl_xor(P, 32);
        if (q == 0)
          Dred[(size_t)seg * H_DIM + h] = P + bproj[h] * gvec[h];
      }
#pragma unroll
      for (int i = 0; i < 8; i++)
#pragma unroll
        for (int j = 0; j < 4; j++) acc[i][j] = (f32x4){0.f, 0.f, 0.f, 0.f};
    }
    buf ^= 1;
  }
#undef STAGEB
#undef ALOAD
#undef AWRITE
}

// ---------------- prefix scan over k + hT (bf16 out) ----------------
__global__ __launch_bounds__(256) void state_kernel(const float* __restrict__ Dred,
                                                    const float* __restrict__ a128v,
                                                    unsigned short* __restrict__ hTbf) {
  int idx = blockIdx.x * 256 + threadIdx.x;  // b*1024 + h, 8192 total
  int b = idx >> 10, h = idx & 1023;
  const float* S = Dred + (size_t)b * KSUB * H_DIM + h;            // corr stream
  const float* Dd = Dred + (size_t)(B_DIM + b) * KSUB * H_DIM + h; // dec stream
  float A = a128v[h];
  float C = 0.f;
  for (int k = 0; k < KSUB; k++) {
    hTbf[((size_t)(b * KSUB + k)) * H_DIM + h] = f2bf(fmaf(A, C, Dd[(size_t)k * H_DIM]));
    C = fmaf(A, C, S[(size_t)k * H_DIM]);
  }
}

// ---------------- MFMA heads ----------------
// head1: y = silu(hT @ W_out + b_out)   M=256, N=1024, K=1024, out bf16
__global__ __launch_bounds__(256) void head1_kernel(const unsigned short* __restrict__ Abf,
                                                    const unsigned short* __restrict__ Bt,
                                                    const float* __restrict__ bias,
                                                    unsigned short* __restrict__ ybf) {
  __shared__ alignas(16) unsigned short As[128 * 32];
  __shared__ alignas(16) unsigned short Bs[128 * 32];
  const int t = threadIdx.x;
  const int lane = t & 63, wave = t >> 6;
  const int bm = blockIdx.x, bn = blockIdx.y;
  const int lo = lane & 15, q = lane >> 4;
  const int wm = wave & 1, wn = wave >> 1;

  f32x4 acc[4][4];
#pragma unroll
  for (int i = 0; i < 4; i++)
#pragma unroll
    for (int j = 0; j < 4; j++) acc[i][j] = (f32x4){0.f, 0.f, 0.f, 0.f};

  const int r0 = t >> 2;
  const int c0 = (t & 3) * 8;
  const unsigned short* Ag0 = Abf + ((size_t)bm * 128 + r0) * 1024 + c0;
  const unsigned short* Ag1 = Abf + ((size_t)bm * 128 + 64 + r0) * 1024 + c0;
  const unsigned short* Bg0 = Bt + ((size_t)bn * 128 + r0) * 1024 + c0;
  const unsigned short* Bg1 = Bt + ((size_t)bn * 128 + 64 + r0) * 1024 + c0;
  unsigned short* Al0 = &As[t * 8];
  unsigned short* Al1 = &As[(256 + t) * 8];
  unsigned short* Bl0 = &Bs[t * 8];
  unsigned short* Bl1 = &Bs[(256 + t) * 8];

  for (int kk = 0; kk < 1024; kk += 32) {
    async16(Ag0 + kk, Al0);
    async16(Ag1 + kk, Al1);
    async16(Bg0 + kk, Bl0);
    async16(Bg1 + kk, Bl1);
    __syncthreads();
    bf16x8 af[4], bv[4];
#pragma unroll
    for (int i = 0; i < 4; i++)
      af[i] = *(const bf16x8*)&As[(wm * 64 + i * 16 + lo) * 32 + q * 8];
#pragma unroll
    for (int j = 0; j < 4; j++)
      bv[j] = *(const bf16x8*)&Bs[(wn * 64 + j * 16 + lo) * 32 + q * 8];
#pragma unroll
    for (int i = 0; i < 4; i++)
#pragma unroll
      for (int j = 0; j < 4; j++)
        acc[i][j] = __builtin_amdgcn_mfma_f32_16x16x32_bf16(af[i], bv[j], acc[i][j], 0, 0, 0);
    __syncthreads();
  }

#pragma unroll
  for (int j = 0; j < 4; j++) {
    const int col = bn * 128 + wn * 64 + j * 16 + lo;
    const float bb = bias[col];
#pragma unroll
    for (int i = 0; i < 4; i++) {
#pragma unroll
      for (int r = 0; r < 4; r++) {
        const int row = bm * 128 + wm * 64 + i * 16 + q * 4 + r;
        float z = acc[i][j][r] + bb;
        float y = z / (1.f + expf(-z));
        ybf[(size_t)row * 1024 + col] = f2bf(y);
      }
    }
  }
}

// head2: [mu|lv] = y @ [W_mu|W_lv] + [b_mu|b_lv]   M=256, N=512, K=1024, out fp32
__global__ __launch_bounds__(256) void head2_kernel(const unsigned short* __restrict__ Abf,
                                                    const unsigned short* __restrict__ Bt,
                                                    const float* __restrict__ bmu,
                                                    const float* __restrict__ blv,
                                                    float* __restrict__ out) {
  __shared__ alignas(16) unsigned short As[128 * 32];
  __shared__ alignas(16) unsigned short Bs[128 * 32];
  const int t = threadIdx.x;
  const int lane = t & 63, wave = t >> 6;
  const int bm = blockIdx.x, bn = blockIdx.y;   // bn 0..3
  const int lo = lane & 15, q = lane >> 4;
  const int wm = wave & 1, wn = wave >> 1;

  f32x4 acc[4][4];
#pragma unroll
  for (int i = 0; i < 4; i++)
#pragma unroll
    for (int j = 0; j < 4; j++) acc[i][j] = (f32x4){0.f, 0.f, 0.f, 0.f};

  const int r0 = t >> 2;
  const int c0 = (t & 3) * 8;
  const unsigned short* Ag0 = Abf + ((size_t)bm * 128 + r0) * 1024 + c0;
  const unsigned short* Ag1 = Abf + ((size_t)bm * 128 + 64 + r0) * 1024 + c0;
  const unsigned short* Bg0 = Bt + ((size_t)bn * 128 + r0) * 1024 + c0;
  const unsigned short* Bg1 = Bt + ((size_t)bn * 128 + 64 + r0) * 1024 + c0;
  unsigned short* Al0 = &As[t * 8];
  unsigned short* Al1 = &As[(256 + t) * 8];
  unsigned short* Bl0 = &Bs[t * 8];
  unsigned short* Bl1 = &Bs[(256 + t) * 8];

  for (int kk = 0; kk < 1024; kk += 32) {
    async16(Ag0 + kk, Al0);
    async16(Ag1 + kk, Al1);
    async16(Bg0 + kk, Bl0);
    async16(Bg1 + kk, Bl1);
    __syncthreads();
    bf16x8 af[4], bv[4];
#pragma unroll
    for (int i = 0; i < 4; i++)
      af[i] = *(const bf16x8*)&As[(wm * 64 + i * 16 + lo) * 32 + q * 8];
#pragma unroll
    for (int j = 0; j < 4; j++)
      bv[j] = *(const bf16x8*)&Bs[(wn * 64 + j * 16 + lo) * 32 + q * 8];
#pragma unroll
    for (int i = 0; i < 4; i++)
#pragma unroll
      for (int j = 0; j < 4; j++)
        acc[i][j] = __builtin_amdgcn_mfma_f32_16x16x32_bf16(af[i], bv[j], acc[i][j], 0, 0, 0);
    __syncthreads();
  }

#pragma unroll
  for (int j = 0; j < 4; j++) {
    const int col = bn * 128 + wn * 64 + j * 16 + lo;   // 0..511
    const float bb = (col < 256) ? bmu[col] : blv[col - 256];
    float* dst = (col < 256) ? (out + col) : (out + 65536 + (col - 256));
#pragma unroll
    for (int i = 0; i < 4; i++) {
#pragma unroll
      for (int r = 0; r < 4; r++) {
        const int row = bm * 128 + wm * 64 + i * 16 + q * 4 + r;
        dst[(size_t)row * 256] = acc[i][j][r] + bb;
      }
    }
  }
}

// ---------------- launcher ----------------
extern "C" void kernel_launch(void* const* d_in, const int* in_sizes, int n_in,
                              void* d_out, int out_size, void* d_ws, size_t ws_size,
                              hipStream_t stream) {
  const float* decoder = (const float*)d_in[0];
  const float* targets = (const float*)d_in[1];
  const float* W_proj = (const float*)d_in[2];
  const float* b_proj = (const float*)d_in[3];
  const float* a_raw = (const float*)d_in[4];
  const float* W_out = (const float*)d_in[5];
  const float* b_out = (const float*)d_in[6];
  const float* W_mu = (const float*)d_in[7];
  const float* b_mu = (const float*)d_in[8];
  const float* W_lv = (const float*)d_in[9];
  const float* b_lv = (const float*)d_in[10];
  float* out = (float*)d_out;

  char* ws = (char*)d_ws;
  unsigned short* WT = (unsigned short*)(ws + 134217728);         // 2097152 B
  float* avec = (float*)(ws + 136314880);                         // 4096 B
  float* gvec = (float*)(ws + 136318976);                         // 4096 B
  float* a128v = (float*)(ws + 136323072);                        // 4096 B
  float* DredP = (float*)(ws + 136327168);                        // 2097152 B -> end 138424320
  // low workspace region:
  unsigned short* hTbf = (unsigned short*)ws;                     // 524288 B
  unsigned short* ybf = (unsigned short*)(ws + 524288);           // 524288 B
  unsigned short* WoutT = (unsigned short*)(ws + 1048576);        // 2097152 B
  unsigned short* WcatT = (unsigned short*)(ws + 3145728);        // 1048576 B

  prep_kernel<<<dim3(16, 16, 5), 256, 0, stream>>>(W_proj, a_raw, W_out, W_mu, W_lv,
                                                   WT, avec, gvec, a128v, WoutT, WcatT);
  gemm_seg_kernel<<<256, 512, 0, stream>>>(targets, decoder, WT, avec, gvec, b_proj, DredP);
  state_kernel<<<32, 256, 0, stream>>>(DredP, a128v, hTbf);
  head1_kernel<<<dim3(2, 8), 256, 0, stream>>>(hTbf, WoutT, b_out, ybf);
  head2_kernel<<<dim3(2, 4), 256, 0, stream>>>(ybf, WcatT, b_mu, b_lv, out);
}